// Round 5
// baseline (120.076 us; speedup 1.0000x reference)
//
#include <hip/hip_runtime.h>
#include <hip/hip_bf16.h>

#define N_TOT 8192
#define BHALF 4096
#define DIM   256
#define INV_T 2.0f   // 1/temperature

typedef __attribute__((ext_vector_type(8))) short bf16x8;
typedef __attribute__((ext_vector_type(4))) float f32x4;

__device__ __forceinline__ float b2f(unsigned short u) {
  union { unsigned u; float f; } cv; cv.u = ((unsigned)u) << 16; return cv.f;
}
__device__ __forceinline__ unsigned short f2b(float f) {
  union { float f; unsigned u; } cv; cv.f = f;
  unsigned u = cv.u;
  u += 0x7FFFu + ((u >> 16) & 1u);  // round-to-nearest-even
  return (unsigned short)(u >> 16);
}

// ---------------------------------------------------------------------------
// Kernel 1: L2-normalize rows of [e_i; e_j] -> bf16 zn[8192][256]
// one wave per row, 4 f32/lane
// ---------------------------------------------------------------------------
__global__ __launch_bounds__(256) void normalize_kernel(
    const float* __restrict__ ei, const float* __restrict__ ej,
    unsigned short* __restrict__ zn) {
  const int wave = threadIdx.x >> 6, lane = threadIdx.x & 63;
  const int row = blockIdx.x * 4 + wave;
  const float* src = (row < BHALF) ? (ei + (size_t)row * DIM)
                                   : (ej + (size_t)(row - BHALF) * DIM);
  float4 v = *reinterpret_cast<const float4*>(src + lane * 4);
  float ss = v.x * v.x + v.y * v.y + v.z * v.z + v.w * v.w;
#pragma unroll
  for (int off = 32; off; off >>= 1) ss += __shfl_xor(ss, off, 64);
  float inv = rsqrtf(ss);
  ushort4 o;
  o.x = f2b(v.x * inv); o.y = f2b(v.y * inv);
  o.z = f2b(v.z * inv); o.w = f2b(v.w * inv);
  *reinterpret_cast<ushort4*>(zn + (size_t)row * DIM + lane * 4) = o;
}

// ---------------------------------------------------------------------------
// Kernel 2: positive-pair logits p[i] = dot(zn[i], zn[i+B]) * (1/T), i < B
// one wave per pair
// ---------------------------------------------------------------------------
__global__ __launch_bounds__(256) void posdot_kernel(
    const unsigned short* __restrict__ zn, float* __restrict__ p) {
  const int wave = threadIdx.x >> 6, lane = threadIdx.x & 63;
  const int i = blockIdx.x * 4 + wave;
  const ushort4 a = *reinterpret_cast<const ushort4*>(zn + (size_t)i * DIM + lane * 4);
  const ushort4 b = *reinterpret_cast<const ushort4*>(zn + (size_t)(i + BHALF) * DIM + lane * 4);
  float s = b2f(a.x) * b2f(b.x) + b2f(a.y) * b2f(b.y) +
            b2f(a.z) * b2f(b.z) + b2f(a.w) * b2f(b.w);
#pragma unroll
  for (int off = 32; off; off >>= 1) s += __shfl_xor(s, off, 64);
  if (lane == 0) p[i] = s * INV_T;
}

// ---------------------------------------------------------------------------
// Kernel 3: S[i] = sum_{j != i} exp(zn_i . zn_j / T)
// 128x128 output tile per block, BK=64, 4 waves (2x2), 4x4 16x16x32 frags/wave.
// LDS tiles XOR-swizzled (rule #21): global_load_lds writes linear; source
// column is pre-swizzled; ds_read applies the same XOR.
// Epilogue: exp + diagonal mask + row-sum + atomicAdd.
// ---------------------------------------------------------------------------
__global__ __launch_bounds__(256) void simexp_kernel(
    const unsigned short* __restrict__ zn, float* __restrict__ S) {
  __shared__ __align__(16) unsigned short As[128 * 64];
  __shared__ __align__(16) unsigned short Bs[128 * 64];
  const int tid = threadIdx.x;
  const int wave = tid >> 6, lane = tid & 63;
  const int bi = blockIdx.x, bj = blockIdx.y;
  const int wr = wave >> 1, wc = wave & 1;

  f32x4 acc[4][4] = {};

  const int fragrow_a = wr * 64 + (lane & 15);
  const int fragrow_b = wc * 64 + (lane & 15);
  const int kcolb = (lane >> 4) * 16;  // byte offset of this lane's 8-elem k-group

  const unsigned short* gA = zn + (size_t)bi * 128 * DIM;
  const unsigned short* gB = zn + (size_t)bj * 128 * DIM;

  // staging constants: chunk = 1024 B = 8 rows of 128 B; 16 chunks per tile
  const int lrow  = lane >> 3;        // row within chunk
  const int lslot = (lane & 7) * 16;  // 16B slot within row (physical/linear)

  for (int kt = 0; kt < 4; ++kt) {
#pragma unroll
    for (int r = 0; r < 4; ++r) {
      const int c = wave * 4 + r;          // wave-uniform chunk id
      const int row = c * 8 + lrow;
      const int colb = lslot ^ ((row & 7) << 4);  // inverse-swizzled source col
      const unsigned short* sA = gA + (size_t)row * DIM + kt * 64 + (colb >> 1);
      const unsigned short* sB = gB + (size_t)row * DIM + kt * 64 + (colb >> 1);
      __builtin_amdgcn_global_load_lds(
          (const __attribute__((address_space(1))) void*)sA,
          (__attribute__((address_space(3))) void*)(As + c * 512), 16, 0, 0);
      __builtin_amdgcn_global_load_lds(
          (const __attribute__((address_space(1))) void*)sB,
          (__attribute__((address_space(3))) void*)(Bs + c * 512), 16, 0, 0);
    }
    __syncthreads();  // drains vmcnt + barrier

#pragma unroll
    for (int ks = 0; ks < 2; ++ks) {
      bf16x8 af[4], bfr[4];
#pragma unroll
      for (int m = 0; m < 4; ++m) {
        const int row = fragrow_a + m * 16;
        const int byt = row * 128 + ((ks * 64 + kcolb) ^ ((row & 7) << 4));
        af[m] = *reinterpret_cast<const bf16x8*>(
            reinterpret_cast<const char*>(As) + byt);
      }
#pragma unroll
      for (int n = 0; n < 4; ++n) {
        const int row = fragrow_b + n * 16;
        const int byt = row * 128 + ((ks * 64 + kcolb) ^ ((row & 7) << 4));
        bfr[n] = *reinterpret_cast<const bf16x8*>(
            reinterpret_cast<const char*>(Bs) + byt);
      }
#pragma unroll
      for (int m = 0; m < 4; ++m)
#pragma unroll
        for (int n = 0; n < 4; ++n)
          acc[m][n] = __builtin_amdgcn_mfma_f32_16x16x32_bf16(
              af[m], bfr[n], acc[m][n], 0, 0, 0);
    }
    __syncthreads();
  }

  // epilogue: exp, mask diagonal, row-sum over 16 columns (lanes), atomicAdd
  const int grow0 = bi * 128 + wr * 64 + (lane >> 4) * 4;  // + m*16 + r
  const int gcol0 = bj * 128 + wc * 64 + (lane & 15);      // + n*16
#pragma unroll
  for (int m = 0; m < 4; ++m) {
    float rs[4] = {0.f, 0.f, 0.f, 0.f};
#pragma unroll
    for (int n = 0; n < 4; ++n) {
      const int gc = gcol0 + n * 16;
#pragma unroll
      for (int r = 0; r < 4; ++r) {
        const int gr = grow0 + m * 16 + r;
        float v = __expf(acc[m][n][r] * INV_T);
        v = (gr == gc) ? 0.f : v;
        rs[r] += v;
      }
    }
#pragma unroll
    for (int off = 1; off < 16; off <<= 1) {
#pragma unroll
      for (int r = 0; r < 4; ++r) rs[r] += __shfl_xor(rs[r], off, 64);
    }
    if ((lane & 15) == 0) {
#pragma unroll
      for (int r = 0; r < 4; ++r)
        atomicAdd(&S[grow0 + m * 16 + r], rs[r]);
    }
  }
}

// ---------------------------------------------------------------------------
// Kernel 4: loss = (1/N) * sum_i (log(S[i]) - p[i % B]), single block
// ---------------------------------------------------------------------------
__global__ __launch_bounds__(256) void finalize_kernel(
    const float* __restrict__ S, const float* __restrict__ p,
    float* __restrict__ out) {
  float acc = 0.f;
  for (int i = threadIdx.x; i < N_TOT; i += 256) {
    const int pi = (i < BHALF) ? i : (i - BHALF);
    acc += logf(S[i]) - p[pi];
  }
#pragma unroll
  for (int off = 32; off; off >>= 1) acc += __shfl_xor(acc, off, 64);
  __shared__ float red[4];
  const int wave = threadIdx.x >> 6, lane = threadIdx.x & 63;
  if (lane == 0) red[wave] = acc;
  __syncthreads();
  if (threadIdx.x == 0)
    out[0] = (red[0] + red[1] + red[2] + red[3]) / (float)N_TOT;
}

// ---------------------------------------------------------------------------
extern "C" void kernel_launch(void* const* d_in, const int* in_sizes, int n_in,
                              void* d_out, int out_size, void* d_ws, size_t ws_size,
                              hipStream_t stream) {
  const float* ei = (const float*)d_in[0];
  const float* ej = (const float*)d_in[1];
  float* out = (float*)d_out;

  char* ws = (char*)d_ws;
  unsigned short* zn = (unsigned short*)ws;                       // 8192*256*2 = 4 MiB
  float* S = (float*)(ws + (size_t)N_TOT * DIM * 2);              // 32 KiB
  float* p = (float*)(ws + (size_t)N_TOT * DIM * 2 + N_TOT * 4);  // 16 KiB

  (void)hipMemsetAsync(S, 0, N_TOT * sizeof(float), stream);
  normalize_kernel<<<N_TOT / 4, 256, 0, stream>>>(ei, ej, zn);
  posdot_kernel<<<BHALF / 4, 256, 0, stream>>>(zn, p);
  dim3 grid(N_TOT / 128, N_TOT / 128);
  simexp_kernel<<<grid, 256, 0, stream>>>(zn, S);
  finalize_kernel<<<1, 256, 0, stream>>>(S, p, out);
}

// Round 6
// 119.881 us; speedup vs baseline: 1.0016x; 1.0016x over previous
//
#include <hip/hip_runtime.h>
#include <hip/hip_bf16.h>

#define N_TOT 8192
#define BHALF 4096
#define DIM   256
#define INV_T 2.0f   // 1/temperature

typedef __attribute__((ext_vector_type(8))) short bf16x8;
typedef __attribute__((ext_vector_type(4))) float f32x4;

__device__ __forceinline__ float b2f(unsigned short u) {
  union { unsigned u; float f; } cv; cv.u = ((unsigned)u) << 16; return cv.f;
}
__device__ __forceinline__ unsigned short f2b(float f) {
  union { float f; unsigned u; } cv; cv.f = f;
  unsigned u = cv.u;
  u += 0x7FFFu + ((u >> 16) & 1u);  // round-to-nearest-even
  return (unsigned short)(u >> 16);
}

// ---------------------------------------------------------------------------
// Kernel 1: L2-normalize rows of [e_i; e_j] -> bf16 zn[8192][256]
// one wave per row; block 0..2047 also zeroes its 4 floats of S (replaces memset)
// ---------------------------------------------------------------------------
__global__ __launch_bounds__(256) void normalize_kernel(
    const float* __restrict__ ei, const float* __restrict__ ej,
    unsigned short* __restrict__ zn, float* __restrict__ S) {
  if (threadIdx.x < 4) S[blockIdx.x * 4 + threadIdx.x] = 0.f;
  const int wave = threadIdx.x >> 6, lane = threadIdx.x & 63;
  const int row = blockIdx.x * 4 + wave;
  const float* src = (row < BHALF) ? (ei + (size_t)row * DIM)
                                   : (ej + (size_t)(row - BHALF) * DIM);
  float4 v = *reinterpret_cast<const float4*>(src + lane * 4);
  float ss = v.x * v.x + v.y * v.y + v.z * v.z + v.w * v.w;
#pragma unroll
  for (int off = 32; off; off >>= 1) ss += __shfl_xor(ss, off, 64);
  float inv = rsqrtf(ss);
  ushort4 o;
  o.x = f2b(v.x * inv); o.y = f2b(v.y * inv);
  o.z = f2b(v.z * inv); o.w = f2b(v.w * inv);
  *reinterpret_cast<ushort4*>(zn + (size_t)row * DIM + lane * 4) = o;
}

// ---------------------------------------------------------------------------
// Kernel 2: upper-triangular tiles only (symmetry: sim = sim^T).
// Tile (a,b), a<=b: 128x128, BK=64, 4 waves (2x2), 16x16x32 MFMA, swizzled LDS.
// Epilogue: exp in place; row sums -> S[rows of a]; for a<b also column sums
// -> S[rows of b]; tiles with b==a+32 extract p[i] = raw diag * INV_T.
// ---------------------------------------------------------------------------
__global__ __launch_bounds__(256) void simexp_kernel(
    const unsigned short* __restrict__ zn, float* __restrict__ S,
    float* __restrict__ p) {
  __shared__ __align__(16) unsigned short As[128 * 64];
  __shared__ __align__(16) unsigned short Bs[128 * 64];
  const int tid = threadIdx.x;
  const int wave = tid >> 6, lane = tid & 63;

  // decode linear block id -> (a,b), a<=b, row-major upper triangle
  int t = blockIdx.x;
  int a = 0;
  while ((a + 1) * 64 - ((a + 1) * a) / 2 <= t) ++a;
  const int b = a + (t - (a * 64 - (a * (a - 1)) / 2));
  const bool offdiag = (b != a);
  const bool need_p = (b == a + 32);

  const int wr = wave >> 1, wc = wave & 1;

  f32x4 acc[4][4] = {};

  const int fragrow_a = wr * 64 + (lane & 15);
  const int fragrow_b = wc * 64 + (lane & 15);
  const int kcolb = (lane >> 4) * 16;

  const unsigned short* gA = zn + (size_t)a * 128 * DIM;
  const unsigned short* gB = zn + (size_t)b * 128 * DIM;

  const int lrow  = lane >> 3;        // row within 8-row chunk
  const int lslot = (lane & 7) * 16;  // linear 16B slot within row

  for (int kt = 0; kt < 4; ++kt) {
#pragma unroll
    for (int r = 0; r < 4; ++r) {
      const int c = wave * 4 + r;
      const int row = c * 8 + lrow;
      const int colb = lslot ^ ((row & 7) << 4);  // inverse-swizzled source col
      const unsigned short* sA = gA + (size_t)row * DIM + kt * 64 + (colb >> 1);
      const unsigned short* sB = gB + (size_t)row * DIM + kt * 64 + (colb >> 1);
      __builtin_amdgcn_global_load_lds(
          (const __attribute__((address_space(1))) void*)sA,
          (__attribute__((address_space(3))) void*)(As + c * 512), 16, 0, 0);
      __builtin_amdgcn_global_load_lds(
          (const __attribute__((address_space(1))) void*)sB,
          (__attribute__((address_space(3))) void*)(Bs + c * 512), 16, 0, 0);
    }
    __syncthreads();

#pragma unroll
    for (int ks = 0; ks < 2; ++ks) {
      bf16x8 af[4], bfr[4];
#pragma unroll
      for (int m = 0; m < 4; ++m) {
        const int row = fragrow_a + m * 16;
        const int byt = row * 128 + ((ks * 64 + kcolb) ^ ((row & 7) << 4));
        af[m] = *reinterpret_cast<const bf16x8*>(
            reinterpret_cast<const char*>(As) + byt);
      }
#pragma unroll
      for (int n = 0; n < 4; ++n) {
        const int row = fragrow_b + n * 16;
        const int byt = row * 128 + ((ks * 64 + kcolb) ^ ((row & 7) << 4));
        bfr[n] = *reinterpret_cast<const bf16x8*>(
            reinterpret_cast<const char*>(Bs) + byt);
      }
#pragma unroll
      for (int m = 0; m < 4; ++m)
#pragma unroll
        for (int n = 0; n < 4; ++n)
          acc[m][n] = __builtin_amdgcn_mfma_f32_16x16x32_bf16(
              af[m], bfr[n], acc[m][n], 0, 0, 0);
    }
    __syncthreads();
  }

  // ---- epilogue ----
  const int grow0 = a * 128 + wr * 64 + (lane >> 4) * 4;  // + m*16 + r
  const int gcol0 = b * 128 + wc * 64 + (lane & 15);      // + n*16

  // phase 1: posdot extract (raw), exp-transform in place, diag mask
#pragma unroll
  for (int m = 0; m < 4; ++m)
#pragma unroll
    for (int n = 0; n < 4; ++n)
#pragma unroll
      for (int r = 0; r < 4; ++r) {
        const int gr = grow0 + m * 16 + r;
        const int gc = gcol0 + n * 16;
        const float raw = acc[m][n][r];
        if (need_p && gc == gr + BHALF) p[gr] = raw * INV_T;
        float v = __expf(raw * INV_T);
        if (gr == gc) v = 0.f;  // only possible on diagonal tiles
        acc[m][n][r] = v;
      }

  // phase 2: row sums over columns (lane&15 within group, then n)
#pragma unroll
  for (int m = 0; m < 4; ++m) {
    float rs[4];
#pragma unroll
    for (int r = 0; r < 4; ++r)
      rs[r] = acc[m][0][r] + acc[m][1][r] + acc[m][2][r] + acc[m][3][r];
#pragma unroll
    for (int off = 1; off < 16; off <<= 1) {
#pragma unroll
      for (int r = 0; r < 4; ++r) rs[r] += __shfl_xor(rs[r], off, 64);
    }
    if ((lane & 15) == 0) {
#pragma unroll
      for (int r = 0; r < 4; ++r)
        atomicAdd(&S[grow0 + m * 16 + r], rs[r]);
    }
  }

  // phase 3 (off-diagonal only): column sums -> S[cols] (symmetry)
  if (offdiag) {
#pragma unroll
    for (int n = 0; n < 4; ++n) {
      float cs = 0.f;
#pragma unroll
      for (int m = 0; m < 4; ++m)
#pragma unroll
        for (int r = 0; r < 4; ++r) cs += acc[m][n][r];
      cs += __shfl_xor(cs, 16, 64);
      cs += __shfl_xor(cs, 32, 64);
      if (lane < 16) atomicAdd(&S[gcol0 + n * 16], cs);  // gcol0 has lane&15
    }
  }
}

// ---------------------------------------------------------------------------
// Kernel 3: loss = (1/N) * sum_i (log(S[i]) - p[i % B]), single block
// ---------------------------------------------------------------------------
__global__ __launch_bounds__(256) void finalize_kernel(
    const float* __restrict__ S, const float* __restrict__ p,
    float* __restrict__ out) {
  float acc = 0.f;
  for (int i = threadIdx.x; i < N_TOT; i += 256) {
    const int pi = (i < BHALF) ? i : (i - BHALF);
    acc += logf(S[i]) - p[pi];
  }
#pragma unroll
  for (int off = 32; off; off >>= 1) acc += __shfl_xor(acc, off, 64);
  __shared__ float red[4];
  const int wave = threadIdx.x >> 6, lane = threadIdx.x & 63;
  if (lane == 0) red[wave] = acc;
  __syncthreads();
  if (threadIdx.x == 0)
    out[0] = (red[0] + red[1] + red[2] + red[3]) / (float)N_TOT;
}

// ---------------------------------------------------------------------------
extern "C" void kernel_launch(void* const* d_in, const int* in_sizes, int n_in,
                              void* d_out, int out_size, void* d_ws, size_t ws_size,
                              hipStream_t stream) {
  const float* ei = (const float*)d_in[0];
  const float* ej = (const float*)d_in[1];
  float* out = (float*)d_out;

  char* ws = (char*)d_ws;
  unsigned short* zn = (unsigned short*)ws;                       // 4 MiB
  float* S = (float*)(ws + (size_t)N_TOT * DIM * 2);              // 32 KiB
  float* p = (float*)(ws + (size_t)N_TOT * DIM * 2 + N_TOT * 4);  // 16 KiB

  normalize_kernel<<<N_TOT / 4, 256, 0, stream>>>(ei, ej, zn, S);
  simexp_kernel<<<(64 * 65) / 2, 256, 0, stream>>>(zn, S, p);
  finalize_kernel<<<1, 256, 0, stream>>>(S, p, out);
}